// Round 14
// baseline (207.621 us; speedup 1.0000x reference)
//
#include <hip/hip_runtime.h>

typedef _Float16 f16;
typedef _Float16 f16x8 __attribute__((ext_vector_type(8)));
typedef float f32x4 __attribute__((ext_vector_type(4)));

constexpr int NN = 50000;
constexpr int NE = 800000;
constexpr int MP = 50048;   // 782 * 64 (padded row count)
constexpr int CAP = 64;     // bucket capacity per node (Poisson(16) tail ~1e-18)
constexpr int SCHUNKS = (NE + 1023) / 1024;  // 782 edge chunks of 1024

// all four weight transposes in one launch: W [K][N] fp32 -> Wt [N][K] f16
__global__ void conv_w_all(const float* __restrict__ W1i, const float* __restrict__ W2i,
                           const float* __restrict__ W1f, const float* __restrict__ W2f,
                           f16* __restrict__ w1it, f16* __restrict__ w2it,
                           f16* __restrict__ w1ft, f16* __restrict__ w2ft) {
  int i = blockIdx.x * 256 + threadIdx.x;  // total 393216
  const float* W; f16* Wt; int K, N, idx;
  if (i < 65536)       { W = W1i; Wt = w1it; K = 128; N = 512; idx = i; }
  else if (i < 196608) { W = W2i; Wt = w2it; K = 512; N = 256; idx = i - 65536; }
  else if (i < 327680) { W = W1f; Wt = w1ft; K = 256; N = 512; idx = i - 196608; }
  else                 { W = W2f; Wt = w2ft; K = 512; N = 128; idx = i - 327680; }
  int n = idx / K, k = idx - n * K;
  Wt[idx] = (f16)W[(size_t)k * N + n];
}

// one wave per node. Half-wave rows: 16B/lane, one wave-gather covers TWO h-rows.
// Fully-batched masked-FMA; garbage slots clamped to row 0, masked. BANDWIDTH-
// BOUND at compulsory unique-row L2 fill (FETCH = 8 XCDs x 43.5K unique rows x
// 512B = 178MB exactly): three structural variants all 55.5-56.2us — frozen.
__global__ __launch_bounds__(256) void agg_kernel(const f16* __restrict__ h,
    const int* __restrict__ cnt, const unsigned short* __restrict__ bucket,
    f16* __restrict__ hagg) {
  int wid = (blockIdx.x * 256 + threadIdx.x) >> 6;
  int l = threadIdx.x & 63;
  if (wid >= NN) return;
  int deg = cnt[wid];
  if (deg > CAP) deg = CAP;
  int s_all = (int)bucket[(size_t)wid * CAP + l];  // lane l holds slot l (garbage if l >= deg)
  const int half = l >> 5;
  const int lc = l & 31;
  const f16* hb = h + lc * 8;
  float a[8] = {0.f, 0.f, 0.f, 0.f, 0.f, 0.f, 0.f, 0.f};
  for (int base = 0; base < CAP; base += 16) {
    if (base >= deg) break;
    f16x8 v[8];
    #pragma unroll
    for (int u = 0; u < 8; ++u) {
      int s = __shfl(s_all, base + 2 * u + half);
      s = ((unsigned)s < (unsigned)NN) ? s : 0;  // clamp garbage slots (masked below)
      v[u] = *(const f16x8*)(hb + (size_t)s * 256);
    }
    #pragma unroll
    for (int u = 0; u < 8; ++u) {
      float m = (base + 2 * u + half < deg) ? 1.f : 0.f;
      #pragma unroll
      for (int j = 0; j < 8; ++j)
        a[j] = fmaf(m, (float)v[u][j], a[j]);
    }
  }
  #pragma unroll
  for (int j = 0; j < 8; ++j) a[j] += __shfl_xor(a[j], 32);
  if (half == 0) {
    f16x8 o;
    #pragma unroll
    for (int j = 0; j < 8; ++j) o[j] = (f16)a[j];
    *(f16x8*)(hagg + (size_t)wid * 256 + lc * 8) = o;
  }
}

// C[M][N] = act(A @ Wt^T + bias). BMxBN tile, BK=64, 4 waves (2x2).
// Single-buffered 24KB LDS; global_load_lds + XOR-swizzled global SOURCE;
// ds_read_b128 frags with matching XOR (k-permutation freedom).
// A_F32: fuses x f32->f16 cvt into staging.
// SCAT: DEDICATED-XCD scatter — blocks with blockIdx%8 in {0,1} run the edge
// scatter; residue r owns dst half [r*25000,(r+1)*25000). Bucket (ushort,
// 3.2MB/half) stays RESIDENT in that XCD's L2 (no gemm stream thrashing it),
// so lines fill completely before write-back (~6MB sequential vs round-12's
// 37MB of random 64B flushes at ~1TB/s DRAM efficiency). Edge reads are
// nontemporal (no L2 pollution). Gemm blocks use residues 2-7 with an exact
// 6-way m204 bijection (same-m blocks share an XCD L2).
template<int K, int N, int BM, int BN, bool A_F32, bool RELU, bool OUT_F32, bool SCAT>
__global__ __launch_bounds__(256, 2) void gemm_kernel(
    const void* __restrict__ Ain, const f16* __restrict__ Wt,
    const float* __restrict__ bias, void* __restrict__ Cout, int Mvalid,
    const int* __restrict__ esrc, const int* __restrict__ edst,
    int* __restrict__ cnt, unsigned short* __restrict__ bucket) {
  constexpr int WM = BM / 2, WN = BN / 2;
  constexpr int MI = WM / 16, NJ = WN / 16;
  constexpr int AIT = BM / 32, BIT = BN / 32;
  constexpr int GY = N / BN;
  constexpr int NWG = (MP / BM) * GY;  // gemm-only block count
  __shared__ f16 As[BM * 64];
  __shared__ f16 Bs[BN * 64];

  int v;
  if constexpr (SCAT) {
    const int b = blockIdx.x;
    const int p8 = b & 7;
    if (p8 < 2) {
      // scatter block on XCD p8: owns dst half [p8*25000, p8*25000+25000)
      const int sc = b >> 3;            // ordinal within residue, [0, 522)
      const int dlo = p8 * 25000;
      for (int chunk = sc; chunk < SCHUNKS; chunk += 522) {
        int e0 = chunk * 1024 + (int)threadIdx.x;
        #pragma unroll
        for (int i = 0; i < 4; ++i) {
          int e = e0 + i * 256;
          if (e < NE) {
            int d = __builtin_nontemporal_load(edst + e);
            if ((unsigned)(d - dlo) < 25000u) {
              int s = __builtin_nontemporal_load(esrc + e);
              int slot = atomicAdd(&cnt[d], 1);
              if (slot < CAP) bucket[(size_t)d * CAP + slot] = (unsigned short)s;
            }
          }
        }
      }
      return;
    }
    // gemm block on XCD p8 in {2..7}: exact bijection onto [0, NWG)
    const int xcd6 = p8 - 2;            // 0..5
    const int lid = b >> 3;             // [0, 522)
    constexpr int q = NWG / 6, r = NWG % 6;  // 521, 2
    const int sz = (xcd6 < r) ? q + 1 : q;
    if (lid >= sz) return;              // 4 spare blocks
    v = (xcd6 < r ? xcd6 * (q + 1) : r * (q + 1) + (xcd6 - r) * q) + lid;
  } else {
    // bijective XCD swizzle over the NWG gemm blocks (m204)
    const int orig = blockIdx.x;
    const int xcd = orig & 7, lid = orig >> 3;
    constexpr int q = NWG >> 3, r = NWG & 7;
    v = (xcd < r ? xcd * (q + 1) : r * (q + 1) + (xcd - r) * q) + lid;
  }
  const int m0 = (v / GY) * BM;
  const int n0 = (v % GY) * BN;
  const int t = threadIdx.x;
  const int w = t >> 6, l = t & 63;
  const int wm = (w >> 1) * WM, wn = (w & 1) * WN;
  const int lg = l >> 4, lr = l & 15;
  // staging: per instr, 32 rows x 8 chunks of 16B; physical chunk pc holds
  // logical chunk pc ^ (row & 7)
  const int rs = t >> 3, pc = t & 7;
  f32x4 acc[MI][NJ] = {};
  for (int kt = 0; kt < K; kt += 64) {
    #pragma unroll
    for (int it = 0; it < AIT; ++it) {
      int rr = it * 32 + rs;
      int lc = pc ^ (rr & 7);
      if constexpr (A_F32) {
        int rg = m0 + rr; if (rg > NN - 1) rg = NN - 1;  // pad rows: any valid data
        const float4* p = (const float4*)((const float*)Ain + (size_t)rg * K + kt + lc * 8);
        float4 u0 = p[0], u1 = p[1];
        f16x8 o = {(f16)u0.x, (f16)u0.y, (f16)u0.z, (f16)u0.w,
                   (f16)u1.x, (f16)u1.y, (f16)u1.z, (f16)u1.w};
        *(f16x8*)(As + (it * 256 + t) * 8) = o;
      } else {
        __builtin_amdgcn_global_load_lds(
            (const __attribute__((address_space(1))) void*)((const f16*)Ain + (size_t)(m0 + rr) * K + kt + lc * 8),
            (__attribute__((address_space(3))) void*)(As + (it * 256 + t) * 8), 16, 0, 0);
      }
    }
    #pragma unroll
    for (int it = 0; it < BIT; ++it) {
      int rr = it * 32 + rs;
      int lc = pc ^ (rr & 7);
      __builtin_amdgcn_global_load_lds(
          (const __attribute__((address_space(1))) void*)(Wt + (size_t)(n0 + rr) * K + kt + lc * 8),
          (__attribute__((address_space(3))) void*)(Bs + (it * 256 + t) * 8), 16, 0, 0);
    }
    __syncthreads();  // drains vmcnt+lgkmcnt before barrier
    #pragma unroll
    for (int kk = 0; kk < 64; kk += 32) {
      const int c = (kk >> 3) + lg;  // logical chunk: slot j of group lg <-> k = kk + lg*8 + j
      f16x8 af[MI], bf[NJ];
      #pragma unroll
      for (int i = 0; i < MI; ++i) {
        int ra = wm + i * 16 + lr;
        af[i] = *(const f16x8*)&As[ra * 64 + ((c ^ (ra & 7)) << 3)];
      }
      #pragma unroll
      for (int j = 0; j < NJ; ++j) {
        int rb = wn + j * 16 + lr;
        bf[j] = *(const f16x8*)&Bs[rb * 64 + ((c ^ (rb & 7)) << 3)];
      }
      #pragma unroll
      for (int i = 0; i < MI; ++i)
        #pragma unroll
        for (int j = 0; j < NJ; ++j)
          acc[i][j] = __builtin_amdgcn_mfma_f32_16x16x32_f16(af[i], bf[j], acc[i][j], 0, 0, 0);
    }
    __syncthreads();
  }
  // epilogue: C/D layout col = lane&15, row = (lane>>4)*4 + reg
  #pragma unroll
  for (int i = 0; i < MI; ++i) {
    #pragma unroll
    for (int j = 0; j < NJ; ++j) {
      int n = n0 + wn + j * 16 + lr;
      float bv = bias[n];
      #pragma unroll
      for (int rg = 0; rg < 4; ++rg) {
        int m = m0 + wm + i * 16 + lg * 4 + rg;
        float vv = acc[i][j][rg] + bv;
        if (RELU) vv = vv > 0.f ? vv : 0.f;
        if (OUT_F32) {
          if (m < Mvalid) ((float*)Cout)[(size_t)m * N + n] = vv;
        } else {
          ((f16*)Cout)[(size_t)m * N + n] = (f16)vv;
        }
      }
    }
  }
}

extern "C" void kernel_launch(void* const* d_in, const int* in_sizes, int n_in,
                              void* d_out, int out_size, void* d_ws, size_t ws_size,
                              hipStream_t stream) {
  const float* x   = (const float*)d_in[0];
  const int*   ei  = (const int*)d_in[1];   // [2][NE]: row0 = src, row1 = dst
  const float* W1i = (const float*)d_in[2];
  const float* b1i = (const float*)d_in[3];
  const float* W2i = (const float*)d_in[4];
  const float* b2i = (const float*)d_in[5];
  const float* W1f = (const float*)d_in[6];
  const float* b1f = (const float*)d_in[7];
  const float* W2f = (const float*)d_in[8];
  const float* b2f = (const float*)d_in[9];
  float* out = (float*)d_out;

  char* ws = (char*)d_ws;
  size_t off = 0;
  auto alloc = [&](size_t bytes) -> void* {
    void* p = ws + off;
    off += (bytes + 255) & ~(size_t)255;
    return p;
  };
  f16* w1it  = (f16*)alloc((size_t)512 * 128 * 2);
  f16* w2it  = (f16*)alloc((size_t)256 * 512 * 2);
  f16* w1ft  = (f16*)alloc((size_t)512 * 256 * 2);
  f16* w2ft  = (f16*)alloc((size_t)128 * 512 * 2);
  f16* hid   = (f16*)alloc((size_t)MP * 512 * 2);  // reused for hidden1 and hidden2
  f16* h     = (f16*)alloc((size_t)MP * 256 * 2);
  f16* hagg  = (f16*)alloc((size_t)MP * 256 * 2);
  int* cnt   = (int*)alloc((size_t)NN * 4);
  unsigned short* bucket = (unsigned short*)alloc((size_t)NN * CAP * 2);

  hipMemsetAsync(cnt, 0, (size_t)NN * 4, stream);
  conv_w_all<<<393216 / 256, 256, 0, stream>>>(W1i, W2i, W1f, W2f, w1it, w2it, w1ft, w2ft);

  // G1 with dedicated-XCD edge scatter: 522 periods of 8 (2 scatter + 6 gemm)
  gemm_kernel<128, 512, 64, 128, true,  true,  false, true >
      <<<522 * 8, 256, 0, stream>>>(x, w1it, b1i, hid, MP,
                                    ei, ei + NE, cnt, bucket);
  gemm_kernel<512, 256, 64, 128, false, false, false, false>
      <<<(MP / 64) * 2, 256, 0, stream>>>(hid, w2it, b2i, h, MP,
                                          nullptr, nullptr, nullptr, nullptr);
  agg_kernel<<<(NN * 64) / 256, 256, 0, stream>>>(h, cnt, bucket, hagg);
  gemm_kernel<256, 512, 64, 128, false, true,  false, false>
      <<<(MP / 64) * 4, 256, 0, stream>>>(hagg, w1ft, b1f, hid, MP,
                                          nullptr, nullptr, nullptr, nullptr);
  gemm_kernel<512, 128, 64, 64,  false, false, true,  false>
      <<<(MP / 64) * 2, 256, 0, stream>>>(hid, w2ft, b2f, out, NN,
                                          nullptr, nullptr, nullptr, nullptr);
}

// Round 15
// 171.116 us; speedup vs baseline: 1.2133x; 1.2133x over previous
//
#include <hip/hip_runtime.h>

typedef _Float16 f16;
typedef _Float16 f16x8 __attribute__((ext_vector_type(8)));
typedef float f32x4 __attribute__((ext_vector_type(4)));

constexpr int NN = 50000;
constexpr int NE = 800000;
constexpr int MP = 50048;   // 782 * 64 (padded row count)
constexpr int CAP = 64;     // bucket capacity per node (Poisson(16) tail ~1e-18)
constexpr int DSLICE = 6250;                 // NN / 8 dsts per XCD slice
constexpr int SCHUNKS = (NE + 1023) / 1024;  // 782 edge chunks of 1024

// all four weight transposes in one launch: W [K][N] fp32 -> Wt [N][K] f16
__global__ void conv_w_all(const float* __restrict__ W1i, const float* __restrict__ W2i,
                           const float* __restrict__ W1f, const float* __restrict__ W2f,
                           f16* __restrict__ w1it, f16* __restrict__ w2it,
                           f16* __restrict__ w1ft, f16* __restrict__ w2ft) {
  int i = blockIdx.x * 256 + threadIdx.x;  // total 393216
  const float* W; f16* Wt; int K, N, idx;
  if (i < 65536)       { W = W1i; Wt = w1it; K = 128; N = 512; idx = i; }
  else if (i < 196608) { W = W2i; Wt = w2it; K = 512; N = 256; idx = i - 65536; }
  else if (i < 327680) { W = W1f; Wt = w1ft; K = 256; N = 512; idx = i - 196608; }
  else                 { W = W2f; Wt = w2ft; K = 512; N = 128; idx = i - 327680; }
  int n = idx / K, k = idx - n * K;
  Wt[idx] = (f16)W[(size_t)k * N + n];
}

// one wave per node. Half-wave rows: 16B/lane, one wave-gather covers TWO h-rows.
// Fully-batched masked-FMA accumulation; garbage slots clamped to row 0, masked.
// BANDWIDTH-BOUND at compulsory per-XCD L2-fill (~178MB): three structural
// variants all 55.5-56.2us — frozen.
__global__ __launch_bounds__(256) void agg_kernel(const f16* __restrict__ h,
    const int* __restrict__ cnt, const int* __restrict__ bucket,
    f16* __restrict__ hagg) {
  int wid = (blockIdx.x * 256 + threadIdx.x) >> 6;
  int l = threadIdx.x & 63;
  if (wid >= NN) return;
  int deg = cnt[wid];
  if (deg > CAP) deg = CAP;
  int s_all = bucket[(size_t)wid * CAP + l];  // lane l holds slot l (garbage if l >= deg)
  const int half = l >> 5;
  const int lc = l & 31;
  const f16* hb = h + lc * 8;
  float a[8] = {0.f, 0.f, 0.f, 0.f, 0.f, 0.f, 0.f, 0.f};
  for (int base = 0; base < CAP; base += 16) {
    if (base >= deg) break;
    f16x8 v[8];
    #pragma unroll
    for (int u = 0; u < 8; ++u) {
      int s = __shfl(s_all, base + 2 * u + half);
      s = ((unsigned)s < (unsigned)NN) ? s : 0;  // clamp garbage slots (masked below)
      v[u] = *(const f16x8*)(hb + (size_t)s * 256);
    }
    #pragma unroll
    for (int u = 0; u < 8; ++u) {
      float m = (base + 2 * u + half < deg) ? 1.f : 0.f;
      #pragma unroll
      for (int j = 0; j < 8; ++j)
        a[j] = fmaf(m, (float)v[u][j], a[j]);
    }
  }
  #pragma unroll
  for (int j = 0; j < 8; ++j) a[j] += __shfl_xor(a[j], 32);
  if (half == 0) {
    f16x8 o;
    #pragma unroll
    for (int j = 0; j < 8; ++j) o[j] = (f16)a[j];
    *(f16x8*)(hagg + (size_t)wid * 256 + lc * 8) = o;
  }
}

// C[M][N] = act(A @ Wt^T + bias). BMxBN tile, BK=64, 4 waves (2x2).
// Single-buffered 24KB LDS, ~5-6 blocks/CU; implicit inter-block overlap (m114).
// global_load_lds + XOR-swizzled global SOURCE; ds_read_b128 frags with matching
// XOR (k-permutation freedom). A_F32: fuses x f32->f16 cvt into staging.
// SCAT: scatter blocks INTERLEAVED with gemm blocks (period-24 pattern, 1 gemm :
// 2 scatter) so memory-bound scatter co-resides with MFMA-bound gemm blocks.
// slice = blockIdx&7 keeps bucket writes statistically XCD-local; per-period CRT
// gives each residue exactly 2 scatter chunks. (Dedicated-XCD variant with
// L2-resident ushort bucket REGRESSED — round 14: blockIdx%8->XCD placement is
// not reliable enough to engineer L2 residency; WRITE_SIZE stayed 88MB.)
template<int K, int N, int BM, int BN, bool A_F32, bool RELU, bool OUT_F32, bool SCAT>
__global__ __launch_bounds__(256, 2) void gemm_kernel(
    const void* __restrict__ Ain, const f16* __restrict__ Wt,
    const float* __restrict__ bias, void* __restrict__ Cout, int Mvalid,
    const int* __restrict__ esrc, const int* __restrict__ edst,
    int* __restrict__ cnt, int* __restrict__ bucket) {
  constexpr int WM = BM / 2, WN = BN / 2;
  constexpr int MI = WM / 16, NJ = WN / 16;
  constexpr int AIT = BM / 32, BIT = BN / 32;
  constexpr int GY = N / BN;
  constexpr int NWG = (MP / BM) * GY;  // gemm-only block count
  __shared__ f16 As[BM * 64];
  __shared__ f16 Bs[BN * 64];

  int v;
  if constexpr (SCAT) {
    const int b = blockIdx.x;
    const int p24 = b % 24;
    if (p24 % 3 != 0) {
      // scatter block: slice = own XCD residue; chunk via period-24 ordinal
      const int slice = b & 7;
      const int chunk = (b / 24) * 2 + ((0x00DB2400u >> p24) & 1);
      const int dlo = slice * DSLICE;
      #pragma unroll
      for (int i = 0; i < 4; ++i) {
        int e = chunk * 1024 + i * 256 + (int)threadIdx.x;
        if (e < NE) {
          int d = edst[e];
          if ((unsigned)(d - dlo) < (unsigned)DSLICE) {
            int slot = atomicAdd(&cnt[d], 1);
            if (slot < CAP) bucket[(size_t)d * CAP + slot] = esrc[e];
          }
        }
      }
      return;
    }
    // gemm block: u = b/3 bijective; per-XCD contiguous v-range
    const int u = b / 3;
    const int xcd = b & 7;
    v = xcd * (NWG / 8) + (u >> 3);
  } else {
    // bijective XCD swizzle over the NWG gemm blocks (m204)
    const int orig = blockIdx.x;
    const int xcd = orig & 7, lid = orig >> 3;
    constexpr int q = NWG >> 3, r = NWG & 7;
    v = (xcd < r ? xcd * (q + 1) : r * (q + 1) + (xcd - r) * q) + lid;
  }
  const int m0 = (v / GY) * BM;
  const int n0 = (v % GY) * BN;
  const int t = threadIdx.x;
  const int w = t >> 6, l = t & 63;
  const int wm = (w >> 1) * WM, wn = (w & 1) * WN;
  const int lg = l >> 4, lr = l & 15;
  // staging: per instr, 32 rows x 8 chunks of 16B; physical chunk pc holds
  // logical chunk pc ^ (row & 7)
  const int rs = t >> 3, pc = t & 7;
  f32x4 acc[MI][NJ] = {};
  for (int kt = 0; kt < K; kt += 64) {
    #pragma unroll
    for (int it = 0; it < AIT; ++it) {
      int rr = it * 32 + rs;
      int lc = pc ^ (rr & 7);
      if constexpr (A_F32) {
        int rg = m0 + rr; if (rg > NN - 1) rg = NN - 1;  // pad rows: any valid data
        const float4* p = (const float4*)((const float*)Ain + (size_t)rg * K + kt + lc * 8);
        float4 u0 = p[0], u1 = p[1];
        f16x8 o = {(f16)u0.x, (f16)u0.y, (f16)u0.z, (f16)u0.w,
                   (f16)u1.x, (f16)u1.y, (f16)u1.z, (f16)u1.w};
        *(f16x8*)(As + (it * 256 + t) * 8) = o;
      } else {
        __builtin_amdgcn_global_load_lds(
            (const __attribute__((address_space(1))) void*)((const f16*)Ain + (size_t)(m0 + rr) * K + kt + lc * 8),
            (__attribute__((address_space(3))) void*)(As + (it * 256 + t) * 8), 16, 0, 0);
      }
    }
    #pragma unroll
    for (int it = 0; it < BIT; ++it) {
      int rr = it * 32 + rs;
      int lc = pc ^ (rr & 7);
      __builtin_amdgcn_global_load_lds(
          (const __attribute__((address_space(1))) void*)(Wt + (size_t)(n0 + rr) * K + kt + lc * 8),
          (__attribute__((address_space(3))) void*)(Bs + (it * 256 + t) * 8), 16, 0, 0);
    }
    __syncthreads();  // drains vmcnt+lgkmcnt before barrier
    #pragma unroll
    for (int kk = 0; kk < 64; kk += 32) {
      const int c = (kk >> 3) + lg;  // logical chunk: slot j of group lg <-> k = kk + lg*8 + j
      f16x8 af[MI], bf[NJ];
      #pragma unroll
      for (int i = 0; i < MI; ++i) {
        int ra = wm + i * 16 + lr;
        af[i] = *(const f16x8*)&As[ra * 64 + ((c ^ (ra & 7)) << 3)];
      }
      #pragma unroll
      for (int j = 0; j < NJ; ++j) {
        int rb = wn + j * 16 + lr;
        bf[j] = *(const f16x8*)&Bs[rb * 64 + ((c ^ (rb & 7)) << 3)];
      }
      #pragma unroll
      for (int i = 0; i < MI; ++i)
        #pragma unroll
        for (int j = 0; j < NJ; ++j)
          acc[i][j] = __builtin_amdgcn_mfma_f32_16x16x32_f16(af[i], bf[j], acc[i][j], 0, 0, 0);
    }
    __syncthreads();
  }
  // epilogue: C/D layout col = lane&15, row = (lane>>4)*4 + reg
  #pragma unroll
  for (int i = 0; i < MI; ++i) {
    #pragma unroll
    for (int j = 0; j < NJ; ++j) {
      int n = n0 + wn + j * 16 + lr;
      float bv = bias[n];
      #pragma unroll
      for (int rg = 0; rg < 4; ++rg) {
        int m = m0 + wm + i * 16 + lg * 4 + rg;
        float vv = acc[i][j][rg] + bv;
        if (RELU) vv = vv > 0.f ? vv : 0.f;
        if (OUT_F32) {
          if (m < Mvalid) ((float*)Cout)[(size_t)m * N + n] = vv;
        } else {
          ((f16*)Cout)[(size_t)m * N + n] = (f16)vv;
        }
      }
    }
  }
}

extern "C" void kernel_launch(void* const* d_in, const int* in_sizes, int n_in,
                              void* d_out, int out_size, void* d_ws, size_t ws_size,
                              hipStream_t stream) {
  const float* x   = (const float*)d_in[0];
  const int*   ei  = (const int*)d_in[1];   // [2][NE]: row0 = src, row1 = dst
  const float* W1i = (const float*)d_in[2];
  const float* b1i = (const float*)d_in[3];
  const float* W2i = (const float*)d_in[4];
  const float* b2i = (const float*)d_in[5];
  const float* W1f = (const float*)d_in[6];
  const float* b1f = (const float*)d_in[7];
  const float* W2f = (const float*)d_in[8];
  const float* b2f = (const float*)d_in[9];
  float* out = (float*)d_out;

  char* ws = (char*)d_ws;
  size_t off = 0;
  auto alloc = [&](size_t bytes) -> void* {
    void* p = ws + off;
    off += (bytes + 255) & ~(size_t)255;
    return p;
  };
  f16* w1it  = (f16*)alloc((size_t)512 * 128 * 2);
  f16* w2it  = (f16*)alloc((size_t)256 * 512 * 2);
  f16* w1ft  = (f16*)alloc((size_t)512 * 256 * 2);
  f16* w2ft  = (f16*)alloc((size_t)128 * 512 * 2);
  f16* hid   = (f16*)alloc((size_t)MP * 512 * 2);  // reused for hidden1 and hidden2
  f16* h     = (f16*)alloc((size_t)MP * 256 * 2);
  f16* hagg  = (f16*)alloc((size_t)MP * 256 * 2);
  int* cnt   = (int*)alloc((size_t)NN * 4);
  int* bucket= (int*)alloc((size_t)NN * CAP * 4);

  hipMemsetAsync(cnt, 0, (size_t)NN * 4, stream);
  conv_w_all<<<393216 / 256, 256, 0, stream>>>(W1i, W2i, W1f, W2f, w1it, w2it, w1ft, w2ft);

  // G1 with interleaved XCD-sliced edge scatter: 3128*3 blocks, 1 gemm : 2 scatter
  gemm_kernel<128, 512, 64, 128, true,  true,  false, true >
      <<<3128 * 3, 256, 0, stream>>>(x, w1it, b1i, hid, MP,
                                     ei, ei + NE, cnt, bucket);
  gemm_kernel<512, 256, 64, 128, false, false, false, false>
      <<<(MP / 64) * 2, 256, 0, stream>>>(hid, w2it, b2i, h, MP,
                                          nullptr, nullptr, nullptr, nullptr);
  agg_kernel<<<(NN * 64) / 256, 256, 0, stream>>>(h, cnt, bucket, hagg);
  gemm_kernel<256, 512, 64, 128, false, true,  false, false>
      <<<(MP / 64) * 4, 256, 0, stream>>>(hagg, w1ft, b1f, hid, MP,
                                          nullptr, nullptr, nullptr, nullptr);
  gemm_kernel<512, 128, 64, 64,  false, false, true,  false>
      <<<(MP / 64) * 2, 256, 0, stream>>>(hid, w2ft, b2f, out, NN,
                                          nullptr, nullptr, nullptr, nullptr);
}